// Round 9
// baseline (89.425 us; speedup 1.0000x reference)
//
#include <hip/hip_runtime.h>
#include <hip/hip_bf16.h>

#define NCAT 16

typedef __attribute__((ext_vector_type(8))) short short8v;
typedef __attribute__((ext_vector_type(4))) float float4v;
typedef __attribute__((ext_vector_type(16))) float f32x16;

__constant__ int c_shift[NCAT] = {0,4,6,8,12,16,19,22,24,28,34,36,42,45,48,51};
__constant__ int c_len[NCAT]   = {4,2,2,4,4,3,3,2,4,6,2,6,3,3,3,3};

// ws layout (bytes):
//   scale  @ 0        (2048 f32)  -> 8192
//   shiftv @ 8192     (2048 f32)  -> 16384
//   G      @ 16384    (16384 f32) -> 81920
//   sv     @ 81920    (128 f32)   -> 82432
//   Wlb    @ 82432    (512 KB)    -> 606720
//   W2p    @ 606720   (16*128*8 f32 = 64 KB) -> 672256
//   Gp16   @ 672256   (8 MB)      -> 9060864
//   svpart @ 9060864  (128 KB)    -> 9191936   need ~9.2 MB

static inline __device__ unsigned pk2(float lo, float hi) {
  float2 f2; f2.x = lo; f2.y = hi;
  __hip_bfloat162 h = __float22bfloat162_rn(f2);
  unsigned u; __builtin_memcpy(&u, &h, 4);
  return u;
}
static inline __device__ float bf2f(unsigned short v) {
  unsigned u = (unsigned)v << 16;
  float f; __builtin_memcpy(&f, &u, 4);
  return f;
}

// ---------------------------------------------------------------------------
// K1: blocks 0..255 = MFMA Gram (256 rows each, 16 waves, 32x32 tiles,
// bf16-packed partials, no atomics). Blocks 256..271 = W1 pre-swizzle into
// MFMA B-frag layout + padded W2p table (one cat per block).
// ---------------------------------------------------------------------------
template<bool PART>
__global__ __launch_bounds__(1024) void k_stats_m(
    const float* __restrict__ F, const float* __restrict__ W1,
    const float* __restrict__ W2,
    float* __restrict__ Gdst, unsigned* __restrict__ Gp16,
    float* __restrict__ sv, float* __restrict__ svpart,
    unsigned short* __restrict__ Wlb, float* __restrict__ W2p)
{
  const int tid = threadIdx.x;
  if (blockIdx.x >= 256) {
    const int cat = (int)blockIdx.x - 256;
    for (int e = tid; e < 2048; e += 1024) {
      const int fid = e >> 6, l = e & 63;
      const int ks = fid >> 3, ct = fid & 7;
      const int kb = 32 * ks + 8 * (l >> 4);
      const int c = cat * 128 + 16 * ct + (l & 15);
      uint4 pk;
      pk.x = pk2(W1[(size_t)(kb + 0) * 2048 + c], W1[(size_t)(kb + 1) * 2048 + c]);
      pk.y = pk2(W1[(size_t)(kb + 2) * 2048 + c], W1[(size_t)(kb + 3) * 2048 + c]);
      pk.z = pk2(W1[(size_t)(kb + 4) * 2048 + c], W1[(size_t)(kb + 5) * 2048 + c]);
      pk.w = pk2(W1[(size_t)(kb + 6) * 2048 + c], W1[(size_t)(kb + 7) * 2048 + c]);
      *(uint4*)(Wlb + ((size_t)(cat * 32 + fid) * 64 + l) * 8) = pk;
    }
    if (tid < 1024) {
      const int c = tid >> 3, s = tid & 7;
      W2p[cat * 1024 + tid] = (s < 6) ? W2[cat * 768 + c * 6 + s] : 0.f;
    }
    return;
  }

  const int rowbase = blockIdx.x * 256;
  const int wid = tid >> 6, lane = tid & 63;
  const int wi = wid >> 2, wj = wid & 3;
  const int i0 = wi * 32, j0 = wj * 32;
  const int lr = lane & 31, lh = lane >> 5;

  f32x16 acc;
  #pragma unroll
  for (int e = 0; e < 16; ++e) acc[e] = 0.f;
  float svacc = 0.f;

  for (int ch = 0; ch < 8; ++ch) {
    #pragma unroll
    for (int h = 0; h < 2; ++h) {
      const int rbase = rowbase + ch * 32 + 16 * h + 8 * lh;
      float fa[8], fb[8];
      #pragma unroll
      for (int j = 0; j < 8; ++j) {
        const float* rp = F + (size_t)(rbase + j) * 128;
        fa[j] = rp[i0 + lr];
        fb[j] = rp[j0 + lr];
      }
      if (wj == 0) {
        #pragma unroll
        for (int j = 0; j < 8; ++j) svacc += fa[j];
      }
      uint4 av4, bv4;
      av4.x = pk2(fa[0], fa[1]); av4.y = pk2(fa[2], fa[3]);
      av4.z = pk2(fa[4], fa[5]); av4.w = pk2(fa[6], fa[7]);
      bv4.x = pk2(fb[0], fb[1]); bv4.y = pk2(fb[2], fb[3]);
      bv4.z = pk2(fb[4], fb[5]); bv4.w = pk2(fb[6], fb[7]);
      acc = __builtin_amdgcn_mfma_f32_32x32x16_bf16(
          __builtin_bit_cast(short8v, av4), __builtin_bit_cast(short8v, bv4),
          acc, 0, 0, 0);
    }
  }

  if (wj == 0) {
    svacc += __shfl_xor(svacc, 32);
    if (lane < 32) {
      if (PART) svpart[blockIdx.x * 128 + i0 + lr] = svacc;
      else      atomicAdd(&sv[i0 + lr], svacc);
    }
  }

  if (PART) {
    unsigned* gp = Gp16 + (size_t)blockIdx.x * 8192;
    #pragma unroll
    for (int t = 0; t < 8; ++t) {
      const int rowe = ((2 * t) & 3) + 8 * (t >> 1) + 4 * lh;   // even row of pair
      gp[((i0 + rowe) >> 1) * 128 + j0 + lr] = pk2(acc[2 * t], acc[2 * t + 1]);
    }
  } else {
    #pragma unroll
    for (int reg = 0; reg < 16; ++reg) {
      const int row = (reg & 3) + 8 * (reg >> 2) + 4 * lh;
      atomicAdd(&Gdst[(i0 + row) * 128 + j0 + lr], acc[reg]);
    }
  }
}

// ---------------------------------------------------------------------------
// K2: reduce partials. b<64: G pairs, 2 threads/elem; b==64: sv. grid 65x256.
// ---------------------------------------------------------------------------
__global__ __launch_bounds__(256) void k_reduce(
    const unsigned* __restrict__ Gp16, const float* __restrict__ svpart,
    float* __restrict__ G, float* __restrict__ sv)
{
  const int b = blockIdx.x, tid = threadIdx.x;
  if (b < 64) {
    const int e = b * 128 + (tid >> 1);      // pair index 0..8191
    const int half = tid & 1;
    float lo = 0.f, hi = 0.f;
    #pragma unroll 4
    for (int p = half * 128; p < half * 128 + 128; ++p) {
      const unsigned u = Gp16[(size_t)p * 8192 + e];
      lo += bf2f((unsigned short)(u & 0xffffu));
      hi += bf2f((unsigned short)(u >> 16));
    }
    lo += __shfl_xor(lo, 1);
    hi += __shfl_xor(hi, 1);
    if (half == 0) {
      const int pr = e >> 7, col = e & 127;
      G[(2 * pr) * 128 + col]     = lo;
      G[(2 * pr + 1) * 128 + col] = hi;
    }
  } else {
    if (tid < 128) {
      float s = 0.f;
      #pragma unroll 8
      for (int p = 0; p < 256; ++p) s += svpart[p * 128 + tid];
      sv[tid] = s;
    }
  }
}

// ---------------------------------------------------------------------------
// K3: BN parameters from Gram matrix. grid 128 x 256.
// ---------------------------------------------------------------------------
__global__ __launch_bounds__(256) void k_params(
    const float* __restrict__ G, const float* __restrict__ sv,
    const float* __restrict__ W1, const float* __restrict__ gamma,
    const float* __restrict__ beta, float* __restrict__ scale,
    float* __restrict__ shiftv)
{
  __shared__ float Gl[128][133];
  __shared__ float Wl[128][16];
  __shared__ float redq[16][16];
  __shared__ float redm[16][16];
  const int tid = threadIdx.x;
  const int jb = blockIdx.x * 16;
  for (int i = tid; i < 16384; i += 256) Gl[i >> 7][i & 127] = G[i];
  for (int i = tid; i < 2048; i += 256) {
    int k = i >> 4, col = i & 15;
    Wl[k][col] = W1[(size_t)k * 2048 + jb + col];
  }
  __syncthreads();
  const int col = tid & 15, part = tid >> 4;
  float msq = 0.f, mean = 0.f;
  for (int ii = 0; ii < 8; ++ii) {
    const int i = part * 8 + ii;
    const float wi = Wl[i][col];
    float inner = 0.f;
    #pragma unroll 8
    for (int k = 0; k < 128; ++k) inner = fmaf(Gl[i][k], Wl[k][col], inner);
    msq = fmaf(wi, inner, msq);
  }
  #pragma unroll
  for (int kk = 0; kk < 8; ++kk) {
    const int k = part * 8 + kk;
    mean = fmaf(sv[k], Wl[k][col], mean);
  }
  redq[part][col] = msq;
  redm[part][col] = mean;
  __syncthreads();
  if (tid < 16) {
    float q = 0.f, m = 0.f;
    #pragma unroll
    for (int p = 0; p < 16; ++p) { q += redq[p][tid]; m += redm[p][tid]; }
    m *= (1.f / 65536.f);
    q *= (1.f / 65536.f);
    float var = q - m * m;
    float sc = gamma[jb + tid] * rsqrtf(var + 1e-5f);
    scale[jb + tid] = sc;
    shiftv[jb + tid] = beta[jb + tid] - m * sc;
  }
}

// ---------------------------------------------------------------------------
// K4: fused main. 1024 blocks x 256 thr (4 waves); block = 64 consecutive
// rows; wave-0 ballot counting-sort by category -> ~16 groups of <=16 rows;
// groups round-robin over 4 waves. W2 from pre-padded W2p (float4 pairs,
// L1-hot). Output via LDS obuf, coalesced block-private dump. 128-VGPR cap
// (proven sufficient R5-R7), ~14.5 KB LDS -> 4 blocks/CU co-resident.
// ---------------------------------------------------------------------------
__global__ __launch_bounds__(256, 4) void k_main(
    const float* __restrict__ F, const unsigned short* __restrict__ Wlb,
    const float* __restrict__ W2p, const float* __restrict__ bias,
    const float* __restrict__ scale, const float* __restrict__ shiftv,
    const int* __restrict__ lab, float* __restrict__ out)
{
  __shared__ float obuf[64 * 54];        // block's output rows (13.5 KB)
  __shared__ unsigned short lrows[64];   // slot -> local row
  __shared__ int wcs[NCAT];
  __shared__ int loff[NCAT + 1];
  __shared__ unsigned char gcat[32], gsub[32];
  __shared__ int gtot;

  const int tid = threadIdx.x;
  const int blk = (int)blockIdx.x;
  const int wid = tid >> 6, lane = tid & 63;
  const int lrow = lane & 15, lhi = lane >> 4;

  // zero obuf
  {
    float2* ob2 = (float2*)obuf;
    for (int i = tid; i < 1728; i += 256) ob2[i] = make_float2(0.f, 0.f);
  }

  // wave-0 ballot histogram + rank over the block's 64 rows
  int myc = 0, myrank = 0;
  if (tid < 64) {
    myc = lab[blk * 64 + tid];
    const unsigned long long lanebit = 1ull << lane;
    #pragma unroll
    for (int cc = 0; cc < NCAT; ++cc) {
      unsigned long long m = __ballot(myc == cc);
      if (lane == 0) wcs[cc] = (int)__popcll(m);
      if (myc == cc) myrank = (int)__popcll(m & (lanebit - 1));
    }
  }
  __syncthreads();
  if (tid == 0) {
    int a = 0, g = 0;
    for (int c = 0; c < NCAT; ++c) {
      loff[c] = a;
      const int cnt = wcs[c];
      for (int s2 = 0; s2 * 16 < cnt; ++s2) {
        gcat[g] = (unsigned char)c; gsub[g] = (unsigned char)s2; ++g;
      }
      a += cnt;
    }
    loff[NCAT] = a;
    gtot = g;
  }
  __syncthreads();
  if (tid < 64) lrows[loff[myc] + myrank] = (unsigned short)tid;
  __syncthreads();

  float bi[6];
  #pragma unroll
  for (int s = 0; s < 6; ++s) bi[s] = bias[s];

  const int ng = gtot;
  for (int g = wid; g < ng; g += 4) {
    const int cat = gcat[g];
    const int slot0 = loff[cat] + ((int)gsub[g] << 4);
    const int hi2 = loff[cat + 1];
    const int navail = min(16, hi2 - slot0);
    const int srow = lrows[min(slot0 + lrow, hi2 - 1)];   // clamped (dup rows)
    const float* fp = F + ((size_t)(blk * 64 + srow)) * 128 + lhi * 8;
    const unsigned short* wbase = Wlb + (size_t)cat * 16384;

    float4v acc[8];
    #pragma unroll
    for (int ct = 0; ct < 8; ++ct) acc[ct] = (float4v){0.f, 0.f, 0.f, 0.f};

    #pragma unroll
    for (int ks = 0; ks < 4; ++ks) {
      const float4 a0 = *(const float4*)(fp + ks * 32);
      const float4 a1 = *(const float4*)(fp + ks * 32 + 4);
      uint4 av4;
      av4.x = pk2(a0.x, a0.y); av4.y = pk2(a0.z, a0.w);
      av4.z = pk2(a1.x, a1.y); av4.w = pk2(a1.z, a1.w);
      const short8v av = __builtin_bit_cast(short8v, av4);
      #pragma unroll
      for (int ct = 0; ct < 8; ++ct) {
        short8v bv = *(const short8v*)(wbase + ((ks * 8 + ct) * 64 + lane) * 8);
        acc[ct] = __builtin_amdgcn_mfma_f32_16x16x32_bf16(av, bv, acc[ct], 0, 0, 0);
      }
    }

    // BN + leaky + W2 partials (lane col c = 16ct+lrow; rows 4*lhi+j)
    float p[4][6];
    #pragma unroll
    for (int j = 0; j < 4; ++j)
      #pragma unroll
      for (int s = 0; s < 6; ++s) p[j][s] = 0.f;
    #pragma unroll
    for (int ct = 0; ct < 8; ++ct) {
      const int c = ct * 16 + lrow;
      const float s_ = scale[cat * 128 + c];
      const float h_ = shiftv[cat * 128 + c];
      const float4* w2p4 = (const float4*)(W2p + ((size_t)cat * 128 + c) * 8);
      const float4 wa = w2p4[0];
      const float4 wb = w2p4[1];
      const float w2v[6] = {wa.x, wa.y, wa.z, wa.w, wb.x, wb.y};
      #pragma unroll
      for (int j = 0; j < 4; ++j) {
        float a = acc[ct][j] * s_ + h_;
        a = (a >= 0.f) ? a : 0.2f * a;
        #pragma unroll
        for (int s = 0; s < 6; ++s) p[j][s] = fmaf(a, w2v[s], p[j][s]);
      }
    }
    // reduce-scatter over the 16-lane group (channels): lvl1/2 keep j == lrow&3
    const bool b1 = (lrow & 1) != 0;
    const bool b2 = (lrow & 2) != 0;
    float q[2][6], r[6];
    #pragma unroll
    for (int t = 0; t < 2; ++t)
      #pragma unroll
      for (int s = 0; s < 6; ++s) {
        float snd = b1 ? p[2 * t][s] : p[2 * t + 1][s];
        float kp  = b1 ? p[2 * t + 1][s] : p[2 * t][s];
        q[t][s] = kp + __shfl_xor(snd, 1);
      }
    #pragma unroll
    for (int s = 0; s < 6; ++s) {
      float snd = b2 ? q[0][s] : q[1][s];
      float kp  = b2 ? q[1][s] : q[0][s];
      r[s] = kp + __shfl_xor(snd, 2);
    }
    #pragma unroll
    for (int s = 0; s < 6; ++s) r[s] += __shfl_xor(r[s], 4);
    #pragma unroll
    for (int s = 0; s < 6; ++s) r[s] += __shfl_xor(r[s], 8);

    const int jj = lrow & 3, sb = lrow >> 2;
    const int jrow = 4 * lhi + jj;
    float pj[6];
    #pragma unroll
    for (int s = 0; s < 6; ++s) pj[s] = r[s] + bi[s];
    float mx = fmaxf(fmaxf(fmaxf(pj[0], pj[1]), fmaxf(pj[2], pj[3])), fmaxf(pj[4], pj[5]));
    float e = __expf(pj[0] - mx) + __expf(pj[1] - mx) + __expf(pj[2] - mx)
            + __expf(pj[3] - mx) + __expf(pj[4] - mx) + __expf(pj[5] - mx);
    float lse = mx + __logf(e);

    if (jrow < navail) {
      const int orow = (int)lrows[slot0 + jrow];
      const int shc = c_shift[cat], lnc = c_len[cat];
      float* ob = obuf + orow * 54 + shc;
      if (sb == 0) {
        ob[0] = pj[0] - lse;
        ob[1] = pj[1] - lse;                 // lnc >= 2 always
        if (lnc > 2) ob[2] = pj[2] - lse;
        if (lnc > 3) ob[3] = pj[3] - lse;
      } else if (sb == 1) {
        if (lnc > 4) ob[4] = pj[4] - lse;
        if (lnc > 5) ob[5] = pj[5] - lse;
      }
    }
  }
  __syncthreads();

  // coalesced dump: block-private, line-aligned 13824-B region
  const float2* ob2 = (const float2*)obuf;
  float2* o2 = (float2*)(out + (size_t)blk * 3456);
  for (int i = tid; i < 1728; i += 256) o2[i] = ob2[i];
}

// ---------------------------------------------------------------------------
// Host launcher — 4 launches (fast path), 3 graph boundaries.
// ---------------------------------------------------------------------------
extern "C" void kernel_launch(void* const* d_in, const int* in_sizes, int n_in,
                              void* d_out, int out_size, void* d_ws, size_t ws_size,
                              hipStream_t stream) {
  const float* F     = (const float*)d_in[0];
  const float* W1    = (const float*)d_in[1];
  const float* gamma = (const float*)d_in[2];
  const float* beta  = (const float*)d_in[3];
  const float* W2    = (const float*)d_in[4];
  const float* bias  = (const float*)d_in[5];
  const int*   lab   = (const int*)d_in[6];
  float* out = (float*)d_out;

  char* ws = (char*)d_ws;
  float* scale   = (float*)(ws + 0);
  float* shiftv  = (float*)(ws + 8192);
  float* G       = (float*)(ws + 16384);
  float* sv      = (float*)(ws + 81920);
  unsigned short* Wlb = (unsigned short*)(ws + 82432);
  float* W2p     = (float*)(ws + 606720);
  unsigned* Gp16 = (unsigned*)(ws + 672256);
  float* svpart  = (float*)(ws + 9060864);

  const size_t need = 9191936;
  if (ws_size >= need) {
    hipLaunchKernelGGL(k_stats_m<true>, dim3(272), dim3(1024), 0, stream,
                       F, W1, W2, G, Gp16, sv, svpart, Wlb, W2p);
    hipLaunchKernelGGL(k_reduce, dim3(65), dim3(256), 0, stream,
                       Gp16, svpart, G, sv);
  } else {
    hipMemsetAsync(ws + 16384, 0, 66048, stream);   // G + sv for atomic path
    hipLaunchKernelGGL(k_stats_m<false>, dim3(272), dim3(1024), 0, stream,
                       F, W1, W2, G, Gp16, sv, svpart, Wlb, W2p);
  }
  hipLaunchKernelGGL(k_params, dim3(128), dim3(256), 0, stream,
                     G, sv, W1, gamma, beta, scale, shiftv);
  hipLaunchKernelGGL(k_main, dim3(1024), dim3(256), 0, stream,
                     F, Wlb, W2p, bias, scale, shiftv, lab, out);
}

// Round 10
// 70.591 us; speedup vs baseline: 1.2668x; 1.2668x over previous
//
#include <hip/hip_runtime.h>
#include <hip/hip_bf16.h>

#define NCAT 16

typedef __attribute__((ext_vector_type(8))) short short8v;
typedef __attribute__((ext_vector_type(4))) float float4v;
typedef __attribute__((ext_vector_type(16))) float f32x16;

__constant__ int c_shift[NCAT] = {0,4,6,8,12,16,19,22,24,28,34,36,42,45,48,51};
__constant__ int c_len[NCAT]   = {4,2,2,4,4,3,3,2,4,6,2,6,3,3,3,3};

// ws layout (bytes):
//   scale  @ 0        (2048 f32)  -> 8192
//   shiftv @ 8192     (2048 f32)  -> 16384
//   G      @ 16384    (16384 f32) -> 81920
//   sv     @ 81920    (128 f32)   -> 82432
//   Wlb    @ 82432    (512 KB)    -> 606720
//   W2p    @ 606720   (16*128*8 f32 = 64 KB) -> 672256
//   Gp16   @ 672256   (8 MB)      -> 9060864
//   svpart @ 9060864  (128 KB)    -> 9191936   need ~9.2 MB

static inline __device__ unsigned pk2(float lo, float hi) {
  float2 f2; f2.x = lo; f2.y = hi;
  __hip_bfloat162 h = __float22bfloat162_rn(f2);
  unsigned u; __builtin_memcpy(&u, &h, 4);
  return u;
}
static inline __device__ float bf2f(unsigned short v) {
  unsigned u = (unsigned)v << 16;
  float f; __builtin_memcpy(&f, &u, 4);
  return f;
}

// ---------------------------------------------------------------------------
// K1: blocks 0..255 = MFMA Gram (256 rows each, 16 waves, 32x32 tiles,
// bf16-packed partials, no atomics). Blocks 256..271 = W1 pre-swizzle into
// MFMA B-frag layout + padded W2p table (one cat per block).
// ---------------------------------------------------------------------------
template<bool PART>
__global__ __launch_bounds__(1024) void k_stats_m(
    const float* __restrict__ F, const float* __restrict__ W1,
    const float* __restrict__ W2,
    float* __restrict__ Gdst, unsigned* __restrict__ Gp16,
    float* __restrict__ sv, float* __restrict__ svpart,
    unsigned short* __restrict__ Wlb, float* __restrict__ W2p)
{
  const int tid = threadIdx.x;
  if (blockIdx.x >= 256) {
    const int cat = (int)blockIdx.x - 256;
    for (int e = tid; e < 2048; e += 1024) {
      const int fid = e >> 6, l = e & 63;
      const int ks = fid >> 3, ct = fid & 7;
      const int kb = 32 * ks + 8 * (l >> 4);
      const int c = cat * 128 + 16 * ct + (l & 15);
      uint4 pk;
      pk.x = pk2(W1[(size_t)(kb + 0) * 2048 + c], W1[(size_t)(kb + 1) * 2048 + c]);
      pk.y = pk2(W1[(size_t)(kb + 2) * 2048 + c], W1[(size_t)(kb + 3) * 2048 + c]);
      pk.z = pk2(W1[(size_t)(kb + 4) * 2048 + c], W1[(size_t)(kb + 5) * 2048 + c]);
      pk.w = pk2(W1[(size_t)(kb + 6) * 2048 + c], W1[(size_t)(kb + 7) * 2048 + c]);
      *(uint4*)(Wlb + ((size_t)(cat * 32 + fid) * 64 + l) * 8) = pk;
    }
    if (tid < 1024) {
      const int c = tid >> 3, s = tid & 7;
      W2p[cat * 1024 + tid] = (s < 6) ? W2[cat * 768 + c * 6 + s] : 0.f;
    }
    return;
  }

  const int rowbase = blockIdx.x * 256;
  const int wid = tid >> 6, lane = tid & 63;
  const int wi = wid >> 2, wj = wid & 3;
  const int i0 = wi * 32, j0 = wj * 32;
  const int lr = lane & 31, lh = lane >> 5;

  f32x16 acc;
  #pragma unroll
  for (int e = 0; e < 16; ++e) acc[e] = 0.f;
  float svacc = 0.f;

  for (int ch = 0; ch < 8; ++ch) {
    #pragma unroll
    for (int h = 0; h < 2; ++h) {
      const int rbase = rowbase + ch * 32 + 16 * h + 8 * lh;
      float fa[8], fb[8];
      #pragma unroll
      for (int j = 0; j < 8; ++j) {
        const float* rp = F + (size_t)(rbase + j) * 128;
        fa[j] = rp[i0 + lr];
        fb[j] = rp[j0 + lr];
      }
      if (wj == 0) {
        #pragma unroll
        for (int j = 0; j < 8; ++j) svacc += fa[j];
      }
      uint4 av4, bv4;
      av4.x = pk2(fa[0], fa[1]); av4.y = pk2(fa[2], fa[3]);
      av4.z = pk2(fa[4], fa[5]); av4.w = pk2(fa[6], fa[7]);
      bv4.x = pk2(fb[0], fb[1]); bv4.y = pk2(fb[2], fb[3]);
      bv4.z = pk2(fb[4], fb[5]); bv4.w = pk2(fb[6], fb[7]);
      acc = __builtin_amdgcn_mfma_f32_32x32x16_bf16(
          __builtin_bit_cast(short8v, av4), __builtin_bit_cast(short8v, bv4),
          acc, 0, 0, 0);
    }
  }

  if (wj == 0) {
    svacc += __shfl_xor(svacc, 32);
    if (lane < 32) {
      if (PART) svpart[blockIdx.x * 128 + i0 + lr] = svacc;
      else      atomicAdd(&sv[i0 + lr], svacc);
    }
  }

  if (PART) {
    unsigned* gp = Gp16 + (size_t)blockIdx.x * 8192;
    #pragma unroll
    for (int t = 0; t < 8; ++t) {
      const int rowe = ((2 * t) & 3) + 8 * (t >> 1) + 4 * lh;   // even row of pair
      gp[((i0 + rowe) >> 1) * 128 + j0 + lr] = pk2(acc[2 * t], acc[2 * t + 1]);
    }
  } else {
    #pragma unroll
    for (int reg = 0; reg < 16; ++reg) {
      const int row = (reg & 3) + 8 * (reg >> 2) + 4 * lh;
      atomicAdd(&Gdst[(i0 + row) * 128 + j0 + lr], acc[reg]);
    }
  }
}

// ---------------------------------------------------------------------------
// K2: reduce partials. b<64: G pairs, 2 threads/elem; b==64: sv. grid 65x256.
// ---------------------------------------------------------------------------
__global__ __launch_bounds__(256) void k_reduce(
    const unsigned* __restrict__ Gp16, const float* __restrict__ svpart,
    float* __restrict__ G, float* __restrict__ sv)
{
  const int b = blockIdx.x, tid = threadIdx.x;
  if (b < 64) {
    const int e = b * 128 + (tid >> 1);      // pair index 0..8191
    const int half = tid & 1;
    float lo = 0.f, hi = 0.f;
    #pragma unroll 4
    for (int p = half * 128; p < half * 128 + 128; ++p) {
      const unsigned u = Gp16[(size_t)p * 8192 + e];
      lo += bf2f((unsigned short)(u & 0xffffu));
      hi += bf2f((unsigned short)(u >> 16));
    }
    lo += __shfl_xor(lo, 1);
    hi += __shfl_xor(hi, 1);
    if (half == 0) {
      const int pr = e >> 7, col = e & 127;
      G[(2 * pr) * 128 + col]     = lo;
      G[(2 * pr + 1) * 128 + col] = hi;
    }
  } else {
    if (tid < 128) {
      float s = 0.f;
      #pragma unroll 8
      for (int p = 0; p < 256; ++p) s += svpart[p * 128 + tid];
      sv[tid] = s;
    }
  }
}

// ---------------------------------------------------------------------------
// K3: BN parameters from Gram matrix. grid 128 x 256.
// ---------------------------------------------------------------------------
__global__ __launch_bounds__(256) void k_params(
    const float* __restrict__ G, const float* __restrict__ sv,
    const float* __restrict__ W1, const float* __restrict__ gamma,
    const float* __restrict__ beta, float* __restrict__ scale,
    float* __restrict__ shiftv)
{
  __shared__ float Gl[128][133];
  __shared__ float Wl[128][16];
  __shared__ float redq[16][16];
  __shared__ float redm[16][16];
  const int tid = threadIdx.x;
  const int jb = blockIdx.x * 16;
  for (int i = tid; i < 16384; i += 256) Gl[i >> 7][i & 127] = G[i];
  for (int i = tid; i < 2048; i += 256) {
    int k = i >> 4, col = i & 15;
    Wl[k][col] = W1[(size_t)k * 2048 + jb + col];
  }
  __syncthreads();
  const int col = tid & 15, part = tid >> 4;
  float msq = 0.f, mean = 0.f;
  for (int ii = 0; ii < 8; ++ii) {
    const int i = part * 8 + ii;
    const float wi = Wl[i][col];
    float inner = 0.f;
    #pragma unroll 8
    for (int k = 0; k < 128; ++k) inner = fmaf(Gl[i][k], Wl[k][col], inner);
    msq = fmaf(wi, inner, msq);
  }
  #pragma unroll
  for (int kk = 0; kk < 8; ++kk) {
    const int k = part * 8 + kk;
    mean = fmaf(sv[k], Wl[k][col], mean);
  }
  redq[part][col] = msq;
  redm[part][col] = mean;
  __syncthreads();
  if (tid < 16) {
    float q = 0.f, m = 0.f;
    #pragma unroll
    for (int p = 0; p < 16; ++p) { q += redq[p][tid]; m += redm[p][tid]; }
    m *= (1.f / 65536.f);
    q *= (1.f / 65536.f);
    float var = q - m * m;
    float sc = gamma[jb + tid] * rsqrtf(var + 1e-5f);
    scale[jb + tid] = sc;
    shiftv[jb + tid] = beta[jb + tid] - m * sc;
  }
}

// ---------------------------------------------------------------------------
// K4: fused main. 256 blocks x 512 thr (8 waves); block = 256 consecutive
// rows (4-wave ballot counting-sort -> ~23 groups of <=16 rows, ~70% fill);
// groups round-robin over 8 waves WITH register prefetch of the next group's
// F rows (hides ~700cy load latency under MFMA+epilogue). Output via 55 KB
// LDS obuf, block-private coalesced float4 dump.
// ---------------------------------------------------------------------------
__global__ __launch_bounds__(512, 2) void k_main(
    const float* __restrict__ F, const unsigned short* __restrict__ Wlb,
    const float* __restrict__ W2p, const float* __restrict__ bias,
    const float* __restrict__ scale, const float* __restrict__ shiftv,
    const int* __restrict__ lab, float* __restrict__ out)
{
  __shared__ __attribute__((aligned(16))) float obuf[256 * 54];  // 55.3 KB
  __shared__ unsigned short lrows[256];  // slot -> local row
  __shared__ int wcs[4][NCAT];
  __shared__ int loff[NCAT + 1];
  __shared__ unsigned char gcat[40], gsub[40];
  __shared__ int gtot;

  const int tid = threadIdx.x;
  const int blk = (int)blockIdx.x;
  const int wid = tid >> 6, lane = tid & 63;
  const int lrow = lane & 15, lhi = lane >> 4;

  // zero obuf
  {
    float4* ob4 = (float4*)obuf;
    for (int i = tid; i < 3456; i += 512) ob4[i] = make_float4(0.f, 0.f, 0.f, 0.f);
  }

  // 4-wave ballot histogram + rank over the block's 256 rows
  int myc = 0, myrank = 0;
  if (tid < 256) {
    myc = lab[blk * 256 + tid];
    const unsigned long long lanebit = 1ull << lane;
    #pragma unroll
    for (int cc = 0; cc < NCAT; ++cc) {
      unsigned long long m = __ballot(myc == cc);
      if (lane == 0) wcs[wid][cc] = (int)__popcll(m);
      if (myc == cc) myrank = (int)__popcll(m & (lanebit - 1));
    }
  }
  __syncthreads();
  if (tid == 0) {
    int a = 0, g = 0;
    for (int c = 0; c < NCAT; ++c) {
      loff[c] = a;
      const int cnt = wcs[0][c] + wcs[1][c] + wcs[2][c] + wcs[3][c];
      for (int s2 = 0; s2 * 16 < cnt; ++s2) {
        gcat[g] = (unsigned char)c; gsub[g] = (unsigned char)s2; ++g;
      }
      a += cnt;
    }
    loff[NCAT] = a;
    gtot = g;
  }
  __syncthreads();
  if (tid < 256) {
    int wbase = 0;
    #pragma unroll
    for (int w = 0; w < 4; ++w)
      if (w < wid) wbase += wcs[w][myc];
    lrows[loff[myc] + wbase + myrank] = (unsigned short)tid;
  }
  __syncthreads();

  float bi[6];
  #pragma unroll
  for (int s = 0; s < 6; ++s) bi[s] = bias[s];

  const int ng = gtot;
  int g = wid;
  if (g >= ng) { __syncthreads(); goto dump; }

  {
    float4 cA[4], cB[4];
    {
      const int cat0 = gcat[g];
      const int slot0 = loff[cat0] + ((int)gsub[g] << 4);
      const int hi2 = loff[cat0 + 1];
      const int srow = lrows[min(slot0 + lrow, hi2 - 1)];
      const float* fp = F + ((size_t)(blk * 256 + srow)) * 128 + lhi * 8;
      #pragma unroll
      for (int ks = 0; ks < 4; ++ks) {
        cA[ks] = *(const float4*)(fp + ks * 32);
        cB[ks] = *(const float4*)(fp + ks * 32 + 4);
      }
    }

    for (; g < ng; g += 8) {
      const int cat = gcat[g];
      const int slot0 = loff[cat] + ((int)gsub[g] << 4);
      const int hi2 = loff[cat + 1];
      const int navail = min(16, hi2 - slot0);
      const unsigned short* wbase2 = Wlb + (size_t)cat * 16384;

      // prefetch next group's F rows (overlaps MFMA+epilogue below)
      const int gn = g + 8;
      const bool hn = gn < ng;
      float4 nA[4], nB[4];
      if (hn) {
        const int catn = gcat[gn];
        const int slot0n = loff[catn] + ((int)gsub[gn] << 4);
        const int hi2n = loff[catn + 1];
        const int srown = lrows[min(slot0n + lrow, hi2n - 1)];
        const float* fpn = F + ((size_t)(blk * 256 + srown)) * 128 + lhi * 8;
        #pragma unroll
        for (int ks = 0; ks < 4; ++ks) {
          nA[ks] = *(const float4*)(fpn + ks * 32);
          nB[ks] = *(const float4*)(fpn + ks * 32 + 4);
        }
      }

      float4v acc[8];
      #pragma unroll
      for (int ct = 0; ct < 8; ++ct) acc[ct] = (float4v){0.f, 0.f, 0.f, 0.f};

      #pragma unroll
      for (int ks = 0; ks < 4; ++ks) {
        uint4 av4;
        av4.x = pk2(cA[ks].x, cA[ks].y); av4.y = pk2(cA[ks].z, cA[ks].w);
        av4.z = pk2(cB[ks].x, cB[ks].y); av4.w = pk2(cB[ks].z, cB[ks].w);
        const short8v av = __builtin_bit_cast(short8v, av4);
        #pragma unroll
        for (int ct = 0; ct < 8; ++ct) {
          short8v bv = *(const short8v*)(wbase2 + ((ks * 8 + ct) * 64 + lane) * 8);
          acc[ct] = __builtin_amdgcn_mfma_f32_16x16x32_bf16(av, bv, acc[ct], 0, 0, 0);
        }
      }

      // BN + leaky + W2 partials (lane col c = 16ct+lrow; rows 4*lhi+j)
      float p[4][6];
      #pragma unroll
      for (int j = 0; j < 4; ++j)
        #pragma unroll
        for (int s = 0; s < 6; ++s) p[j][s] = 0.f;
      #pragma unroll
      for (int ct = 0; ct < 8; ++ct) {
        const int c = ct * 16 + lrow;
        const float s_ = scale[cat * 128 + c];
        const float h_ = shiftv[cat * 128 + c];
        const float4* w2p4 = (const float4*)(W2p + ((size_t)cat * 128 + c) * 8);
        const float4 wa = w2p4[0];
        const float4 wb = w2p4[1];
        const float w2v[6] = {wa.x, wa.y, wa.z, wa.w, wb.x, wb.y};
        #pragma unroll
        for (int j = 0; j < 4; ++j) {
          float a = acc[ct][j] * s_ + h_;
          a = (a >= 0.f) ? a : 0.2f * a;
          #pragma unroll
          for (int s = 0; s < 6; ++s) p[j][s] = fmaf(a, w2v[s], p[j][s]);
        }
      }
      // reduce-scatter over the 16-lane group: lvl1/2 keep j == lrow&3
      const bool b1 = (lrow & 1) != 0;
      const bool b2 = (lrow & 2) != 0;
      float q[2][6], r[6];
      #pragma unroll
      for (int t = 0; t < 2; ++t)
        #pragma unroll
        for (int s = 0; s < 6; ++s) {
          float snd = b1 ? p[2 * t][s] : p[2 * t + 1][s];
          float kp  = b1 ? p[2 * t + 1][s] : p[2 * t][s];
          q[t][s] = kp + __shfl_xor(snd, 1);
        }
      #pragma unroll
      for (int s = 0; s < 6; ++s) {
        float snd = b2 ? q[0][s] : q[1][s];
        float kp  = b2 ? q[1][s] : q[0][s];
        r[s] = kp + __shfl_xor(snd, 2);
      }
      #pragma unroll
      for (int s = 0; s < 6; ++s) r[s] += __shfl_xor(r[s], 4);
      #pragma unroll
      for (int s = 0; s < 6; ++s) r[s] += __shfl_xor(r[s], 8);

      const int jj = lrow & 3, sb = lrow >> 2;
      const int jrow = 4 * lhi + jj;
      float pj[6];
      #pragma unroll
      for (int s = 0; s < 6; ++s) pj[s] = r[s] + bi[s];
      float mx = fmaxf(fmaxf(fmaxf(pj[0], pj[1]), fmaxf(pj[2], pj[3])), fmaxf(pj[4], pj[5]));
      float e = __expf(pj[0] - mx) + __expf(pj[1] - mx) + __expf(pj[2] - mx)
              + __expf(pj[3] - mx) + __expf(pj[4] - mx) + __expf(pj[5] - mx);
      float lse = mx + __logf(e);

      if (jrow < navail) {
        const int orow = (int)lrows[slot0 + jrow];
        const int shc = c_shift[cat], lnc = c_len[cat];
        float* ob = obuf + orow * 54 + shc;
        if (sb == 0) {
          ob[0] = pj[0] - lse;
          ob[1] = pj[1] - lse;                 // lnc >= 2 always
          if (lnc > 2) ob[2] = pj[2] - lse;
          if (lnc > 3) ob[3] = pj[3] - lse;
        } else if (sb == 1) {
          if (lnc > 4) ob[4] = pj[4] - lse;
          if (lnc > 5) ob[5] = pj[5] - lse;
        }
      }

      if (hn) {
        #pragma unroll
        for (int ks = 0; ks < 4; ++ks) { cA[ks] = nA[ks]; cB[ks] = nB[ks]; }
      }
    }
    __syncthreads();
  }

dump:
  // coalesced dump: block-private, line-aligned 55296-B region
  {
    const float4* ob4 = (const float4*)obuf;
    float4* o4 = (float4*)(out + (size_t)blk * 13824);
    for (int i = tid; i < 3456; i += 512) o4[i] = ob4[i];
  }
}

// ---------------------------------------------------------------------------
// Host launcher — 4 launches (fast path), 3 graph boundaries.
// ---------------------------------------------------------------------------
extern "C" void kernel_launch(void* const* d_in, const int* in_sizes, int n_in,
                              void* d_out, int out_size, void* d_ws, size_t ws_size,
                              hipStream_t stream) {
  const float* F     = (const float*)d_in[0];
  const float* W1    = (const float*)d_in[1];
  const float* gamma = (const float*)d_in[2];
  const float* beta  = (const float*)d_in[3];
  const float* W2    = (const float*)d_in[4];
  const float* bias  = (const float*)d_in[5];
  const int*   lab   = (const int*)d_in[6];
  float* out = (float*)d_out;

  char* ws = (char*)d_ws;
  float* scale   = (float*)(ws + 0);
  float* shiftv  = (float*)(ws + 8192);
  float* G       = (float*)(ws + 16384);
  float* sv      = (float*)(ws + 81920);
  unsigned short* Wlb = (unsigned short*)(ws + 82432);
  float* W2p     = (float*)(ws + 606720);
  unsigned* Gp16 = (unsigned*)(ws + 672256);
  float* svpart  = (float*)(ws + 9060864);

  const size_t need = 9191936;
  if (ws_size >= need) {
    hipLaunchKernelGGL(k_stats_m<true>, dim3(272), dim3(1024), 0, stream,
                       F, W1, W2, G, Gp16, sv, svpart, Wlb, W2p);
    hipLaunchKernelGGL(k_reduce, dim3(65), dim3(256), 0, stream,
                       Gp16, svpart, G, sv);
  } else {
    hipMemsetAsync(ws + 16384, 0, 66048, stream);   // G + sv for atomic path
    hipLaunchKernelGGL(k_stats_m<false>, dim3(272), dim3(1024), 0, stream,
                       F, W1, W2, G, Gp16, sv, svpart, Wlb, W2p);
  }
  hipLaunchKernelGGL(k_params, dim3(128), dim3(256), 0, stream,
                     G, sv, W1, gamma, beta, scale, shiftv);
  hipLaunchKernelGGL(k_main, dim3(256), dim3(512), 0, stream,
                     F, Wlb, W2p, bias, scale, shiftv, lab, out);
}